// Round 7
// baseline (235.191 us; speedup 1.0000x reference)
//
#include <hip/hip_runtime.h>

// KnnConvUnit: B=4, N=8192, K=16, C=64, HID=OUT=128.
// out[b,n,:] = (max_k relu(relu(x@W1+b1)@W2+b2)) @ W3 + b3,
//   x = [f, knn, knn-f]  ->  h1 = relu([knn | f] @ [[Bm],[Aw]] + b1)
//   Bm = W1[64:128]+W1[128:192], Aw = W1[0:64]-W1[128:192]  (K=128 folded GEMM)
// v_mfma_f32_16x16x32_f16 everywhere, shared k-permutation
//   kappa(g,j) = 16*(j>>2) + 4*g + (j&3)
// Round-7 fixes vs round-6:
//   * GRID BUG: block does 32 pts -> grid = 32768/32 = 1024 (was 256: only
//     1/4 of output written -> absmax 2.86). Swizzle decode assumed 1024.
//   * L1 split into two pp-pair passes: concurrent acc 16->8, shorter h1f
//     live ranges -> peak VGPR ~115 < 128 cap, no spill (round-4 lesson:
//     spill at (512,*) cap costs ~160MB scratch traffic).

#define BB 4
#define NN 8192
#define KK 16
#define CC 64
#define HH 128
#define PTS 4   // points per wave

typedef _Float16 f16;
typedef __fp16 h16x2 __attribute__((ext_vector_type(2)));   // builtin's return type
typedef _Float16 f16x8 __attribute__((ext_vector_type(8)));
typedef float f32x4 __attribute__((ext_vector_type(4)));

#define MFMA16(a, b, c) __builtin_amdgcn_mfma_f32_16x16x32_f16(a, b, c, 0, 0, 0)

static __device__ __forceinline__ f16x8 cvt8(f32x4 a0, f32x4 a1) {
  h16x2 c0 = __builtin_amdgcn_cvt_pkrtz(a0[0], a0[1]);
  h16x2 c1 = __builtin_amdgcn_cvt_pkrtz(a0[2], a0[3]);
  h16x2 c2 = __builtin_amdgcn_cvt_pkrtz(a1[0], a1[1]);
  h16x2 c3 = __builtin_amdgcn_cvt_pkrtz(a1[2], a1[3]);
  f16x8 v;
  v[0] = (f16)c0[0]; v[1] = (f16)c0[1]; v[2] = (f16)c1[0]; v[3] = (f16)c1[1];
  v[4] = (f16)c2[0]; v[5] = (f16)c2[1]; v[6] = (f16)c3[0]; v[7] = (f16)c3[1];
  return v;
}

// ---------------- prep: pack weights, fragment-linear f16, kappa k-order ----
// fid 0..31 : L1 A-frags (ht=fid>>2, kt=fid&3): kt<2 -> Bm, kt>=2 -> Aw
// fid 32..63: L2 B-frags (h2t, kt): W2[k][h2t*16+r]
// fid 64..95: L3 A-frags (ot, kt):  W3[k][ot*16+r]
__global__ void prep_pack(const float* __restrict__ W1, const float* __restrict__ W2,
                          const float* __restrict__ W3, f16* __restrict__ ws) {
  int fid = blockIdx.x;
  int l = threadIdx.x;
  int g = l >> 4, r = l & 15;
  f16x8 v;
#pragma unroll
  for (int j = 0; j < 8; ++j) {
    int kl = 16 * (j >> 2) + 4 * g + (j & 3);   // kappa(g,j)
    float x;
    if (fid < 32) {
      int ht = fid >> 2, kt = fid & 3, h = ht * 16 + r;
      if (kt < 2) {
        int k = kt * 32 + kl;
        x = W1[(64 + k) * HH + h] + W1[(128 + k) * HH + h];   // Bm
      } else {
        int k = (kt - 2) * 32 + kl;
        x = W1[k * HH + h] - W1[(128 + k) * HH + h];          // Aw
      }
    } else if (fid < 64) {
      int t = fid - 32, h2t = t >> 2, kt = t & 3;
      x = W2[(kt * 32 + kl) * HH + h2t * 16 + r];
    } else {
      int t = fid - 64, ot = t >> 2, kt = t & 3;
      x = W3[(kt * 32 + kl) * HH + ot * 16 + r];
    }
    v[j] = (f16)x;
  }
  *(f16x8*)(ws + (size_t)fid * 512 + l * 8) = v;
}

// ---------------- main: 32 points/block, 8 waves, 4 pts/wave ----------------
// LDS: wbuf 64 frags (64KB) + pooled 8 frags (8KB) = 73728 B -> 2 blocks/CU
__global__ __launch_bounds__(512, 4) void knn_main(
    const float* __restrict__ f, const int* __restrict__ knn,
    const float* __restrict__ b1, const float* __restrict__ b2,
    const float* __restrict__ b3, const f16* __restrict__ ws,
    float* __restrict__ out) {
  extern __shared__ char smem[];
  f16* wbuf = (f16*)smem;              // 64*512 f16
  f16* pooled = wbuf + 64 * 512;       // 8*512 f16

  const int tid = threadIdx.x;
  const int wave = tid >> 6, lane = tid & 63;
  const int g = lane >> 4, r = lane & 15;

  // XCD-aware swizzle: 1024 wgs, 8 XCDs -> each XCD owns 128 contiguous wgs
  const int wg = (blockIdx.x & 7) * 128 + (blockIdx.x >> 3);
  const int b = wg >> 8;                 // 256 blocks per batch
  const int n0 = (wg & 255) * 32;
  const float* fb = f + (size_t)b * NN * CC;
  const int p0 = wave * PTS;
  const int pg = wave >> 2;              // which 16-point group this wave's pts are in

  // --- issue knn index loads first (longest dependency chain) ---
  int nidx[PTS];
#pragma unroll
  for (int pp = 0; pp < PTS; ++pp)
    nidx[pp] = knn[(size_t)(b * NN + n0 + p0 + pp) * KK + r];

  // --- stage 64 weight frags into LDS (reg-staged, coalesced, linear) ---
  f16x8 st[8];
#pragma unroll
  for (int i = 0; i < 8; ++i)
    st[i] = *(const f16x8*)(ws + (size_t)(i * 512 + tid) * 8);
#pragma unroll
  for (int i = 0; i < 8; ++i)
    *(f16x8*)(wbuf + (size_t)(i * 512 + tid) * 8) = st[i];

  // --- gather B-frags: kt 0,1 = neighbor row (scattered), kt 2,3 = own row ---
  f16x8 bf[PTS][4];
#pragma unroll
  for (int pp = 0; pp < PTS; ++pp) {
    const float* frow = fb + (size_t)nidx[pp] * CC;
    const float* fown = fb + (size_t)(n0 + p0 + pp) * CC;
#pragma unroll
    for (int kt = 0; kt < 4; ++kt) {
      const float* src = (kt < 2) ? (frow + kt * 32) : (fown + (kt - 2) * 32);
      f32x4 a0 = *(const f32x4*)(src + 4 * g);
      f32x4 a1 = *(const f32x4*)(src + 4 * g + 16);
      bf[pp][kt] = cvt8(a0, a1);
    }
  }

  __syncthreads();   // (1) wbuf ready

  // --- L1: C[h][nbr] = [Bm;Aw]^T x [knn;f], K=128; h1 -> registers ---
  // Split into two pp-pair passes to cap live VGPRs (acc 8 not 16).
  f16x8 h1f[PTS][4];
#pragma unroll
  for (int half = 0; half < 2; ++half) {
#pragma unroll
    for (int ht = 0; ht < 8; ++ht) {
      f32x4 a0 = {0.f, 0.f, 0.f, 0.f}, a1 = {0.f, 0.f, 0.f, 0.f};
#pragma unroll
      for (int kt = 0; kt < 4; ++kt) {
        f16x8 wfrag = *(const f16x8*)(wbuf + (size_t)(ht * 4 + kt) * 512 + lane * 8);
        a0 = MFMA16(wfrag, bf[half * 2 + 0][kt], a0);
        a1 = MFMA16(wfrag, bf[half * 2 + 1][kt], a1);
      }
      f32x4 b1v = *(const f32x4*)(b1 + ht * 16 + g * 4);
#pragma unroll
      for (int q = 0; q < 2; ++q) {
        f32x4 acc = q ? a1 : a0;
        float x0 = acc[0] + b1v[0]; x0 = x0 > 0.f ? x0 : 0.f;
        float x1 = acc[1] + b1v[1]; x1 = x1 > 0.f ? x1 : 0.f;
        float x2 = acc[2] + b1v[2]; x2 = x2 > 0.f ? x2 : 0.f;
        float x3 = acc[3] + b1v[3]; x3 = x3 > 0.f ? x3 : 0.f;
        h16x2 lo = __builtin_amdgcn_cvt_pkrtz(x0, x1);
        h16x2 hi = __builtin_amdgcn_cvt_pkrtz(x2, x3);
        int pp = half * 2 + q;
        h1f[pp][ht >> 1][(ht & 1) * 4 + 0] = (f16)lo[0];
        h1f[pp][ht >> 1][(ht & 1) * 4 + 1] = (f16)lo[1];
        h1f[pp][ht >> 1][(ht & 1) * 4 + 2] = (f16)hi[0];
        h1f[pp][ht >> 1][(ht & 1) * 4 + 3] = (f16)hi[1];
      }
    }
  }

  // --- L2: C[nbr][h2] = h1 x W2; pool over nbr = 3 v_max + 2 shfl ---
#pragma unroll
  for (int h2t = 0; h2t < 8; ++h2t) {
    f32x4 c[PTS];
#pragma unroll
    for (int pp = 0; pp < PTS; ++pp) c[pp] = (f32x4){0.f, 0.f, 0.f, 0.f};
#pragma unroll
    for (int kt = 0; kt < 4; ++kt) {
      f16x8 w2f = *(const f16x8*)(wbuf + (size_t)(32 + h2t * 4 + kt) * 512 + lane * 8);
#pragma unroll
      for (int pp = 0; pp < PTS; ++pp) c[pp] = MFMA16(h1f[pp][kt], w2f, c[pp]);
    }
    float b2v = b2[h2t * 16 + r];
#pragma unroll
    for (int pp = 0; pp < PTS; ++pp) {
      float m = fmaxf(fmaxf(c[pp][0], c[pp][1]), fmaxf(c[pp][2], c[pp][3]));
      m = fmaxf(m, __shfl_xor(m, 16, 64));
      m = fmaxf(m, __shfl_xor(m, 32, 64));
      float x = m + b2v;
      f16 pv = (f16)(x > 0.f ? x : 0.f);
      if (g == 0) {
        int p = p0 + pp;   // pooled frag col = p&15, group pg
        pooled[(pg * 4 + (h2t >> 1)) * 512 + ((r >> 2) * 16 + (p & 15)) * 8 +
               (h2t & 1) * 4 + (r & 3)] = pv;
      }
    }
  }

  __syncthreads();   // (2) pooled ready (cross-wave)

  // --- L3: C[od][pt] = W3^T x pooled; wave owns od-tile = wave, 2 pt-groups ---
#pragma unroll
  for (int pgg = 0; pgg < 2; ++pgg) {
    f32x4 a3 = {0.f, 0.f, 0.f, 0.f};
#pragma unroll
    for (int kt = 0; kt < 4; ++kt) {
      f16x8 w3f = *(const f16x8*)(ws + (size_t)(64 + wave * 4 + kt) * 512 + lane * 8);
      f16x8 pf = *(const f16x8*)(pooled + (size_t)(pgg * 4 + kt) * 512 + lane * 8);
      a3 = MFMA16(w3f, pf, a3);
    }
    f32x4 b3v = *(const f32x4*)(b3 + wave * 16 + g * 4);
    f32x4 o;
#pragma unroll
    for (int i = 0; i < 4; ++i) o[i] = a3[i] + b3v[i];
    *(f32x4*)(out + ((size_t)b * NN + n0 + pgg * 16 + r) * HH + wave * 16 + g * 4) = o;
  }
}

extern "C" void kernel_launch(void* const* d_in, const int* in_sizes, int n_in,
                              void* d_out, int out_size, void* d_ws, size_t ws_size,
                              hipStream_t stream) {
  const float* f = (const float*)d_in[0];
  const int* knn = (const int*)d_in[1];
  const float* W1 = (const float*)d_in[2];
  const float* b1 = (const float*)d_in[3];
  const float* W2 = (const float*)d_in[4];
  const float* b2 = (const float*)d_in[5];
  const float* W3 = (const float*)d_in[6];
  const float* b3 = (const float*)d_in[7];
  float* outp = (float*)d_out;
  f16* wsp = (f16*)d_ws;   // 96 frags * 1KB = 96KB scratch

  (void)hipFuncSetAttribute((const void*)knn_main,
                            hipFuncAttributeMaxDynamicSharedMemorySize, 73728);

  prep_pack<<<96, 64, 0, stream>>>(W1, W2, W3, wsp);
  // 32 points per block (8 waves x PTS=4) -> grid = 32768/32 = 1024
  knn_main<<<(BB * NN) / (8 * PTS), 512, 73728, stream>>>(f, knn, b1, b2, b3, wsp, outp);
}

// Round 8
// 66.385 us; speedup vs baseline: 3.5428x; 3.5428x over previous
//
#include <hip/hip_runtime.h>

// KnnConvUnit: B=4, N=8192, K=16, C=64, HID=OUT=128.
// out[b,n,:] = (max_k relu(relu(x@W1+b1)@W2+b2)) @ W3 + b3,
//   x = [f, knn, knn-f]  ->  h1 = relu([knn | f] @ [[Bm],[Aw]] + b1)
//   Bm = W1[64:128]+W1[128:192], Aw = W1[0:64]-W1[128:192]  (K=128 folded GEMM)
// v_mfma_f32_16x16x32_f16 everywhere, shared k-permutation
//   kappa(g,j) = 16*(j>>2) + 4*g + (j&3)
// Round-8 = round-2 skeleton (PTS=2, proven 55us, VGPR 56) with:
//   * W2 frags read from GLOBAL ws in L2 (L1/L2-resident, same 32KB for all
//     waves) -> LDS = Bm/Aw 32KB + pooled 4KB = 36864B -> 4 blocks/CU
//   * launch_bounds(512,4) KEPT (cap 128). Round 4's regression was the
//     (512,6) cap=85 -> spill, not the W2 move. Rounds 4/7 law: >~100 live
//     VGPRs at 512 thr => scratch thrash (WRITE_SIZE balloons). PTS stays 2.

#define BB 4
#define NN 8192
#define KK 16
#define CC 64
#define HH 128

typedef _Float16 f16;
typedef __fp16 h16x2 __attribute__((ext_vector_type(2)));   // cvt_pkrtz return type
typedef _Float16 f16x8 __attribute__((ext_vector_type(8)));
typedef float f32x4 __attribute__((ext_vector_type(4)));

#define MFMA16(a, b, c) __builtin_amdgcn_mfma_f32_16x16x32_f16(a, b, c, 0, 0, 0)

static __device__ __forceinline__ f16x8 cvt8(f32x4 a0, f32x4 a1) {
  h16x2 c0 = __builtin_amdgcn_cvt_pkrtz(a0[0], a0[1]);
  h16x2 c1 = __builtin_amdgcn_cvt_pkrtz(a0[2], a0[3]);
  h16x2 c2 = __builtin_amdgcn_cvt_pkrtz(a1[0], a1[1]);
  h16x2 c3 = __builtin_amdgcn_cvt_pkrtz(a1[2], a1[3]);
  f16x8 v;
  v[0] = (f16)c0[0]; v[1] = (f16)c0[1]; v[2] = (f16)c1[0]; v[3] = (f16)c1[1];
  v[4] = (f16)c2[0]; v[5] = (f16)c2[1]; v[6] = (f16)c3[0]; v[7] = (f16)c3[1];
  return v;
}

// ---------------- prep: pack weights, fragment-linear f16, kappa k-order ----
// fid 0..31 : L1 A-frags (ht=fid>>2, kt=fid&3): kt<2 -> Bm, kt>=2 -> Aw
// fid 32..63: L2 B-frags (h2t, kt): W2[k][h2t*16+r]
// fid 64..95: L3 A-frags (ot, kt):  W3[k][ot*16+r]
__global__ void prep_pack(const float* __restrict__ W1, const float* __restrict__ W2,
                          const float* __restrict__ W3, f16* __restrict__ ws) {
  int fid = blockIdx.x;
  int l = threadIdx.x;
  int g = l >> 4, r = l & 15;
  f16x8 v;
#pragma unroll
  for (int j = 0; j < 8; ++j) {
    int kl = 16 * (j >> 2) + 4 * g + (j & 3);   // kappa(g,j)
    float x;
    if (fid < 32) {
      int ht = fid >> 2, kt = fid & 3, h = ht * 16 + r;
      if (kt < 2) {
        int k = kt * 32 + kl;
        x = W1[(64 + k) * HH + h] + W1[(128 + k) * HH + h];   // Bm
      } else {
        int k = (kt - 2) * 32 + kl;
        x = W1[k * HH + h] - W1[(128 + k) * HH + h];          // Aw
      }
    } else if (fid < 64) {
      int t = fid - 32, h2t = t >> 2, kt = t & 3;
      x = W2[(kt * 32 + kl) * HH + h2t * 16 + r];
    } else {
      int t = fid - 64, ot = t >> 2, kt = t & 3;
      x = W3[(kt * 32 + kl) * HH + ot * 16 + r];
    }
    v[j] = (f16)x;
  }
  *(f16x8*)(ws + (size_t)fid * 512 + l * 8) = v;
}

// ---------------- main: 16 points/block, 8 waves, 2 pts/wave ----------------
// LDS: wbuf 32 frags (32KB, L1 weights) + pooled 4 frags (4KB) = 36864 B
__global__ __launch_bounds__(512, 4) void knn_main(
    const float* __restrict__ f, const int* __restrict__ knn,
    const float* __restrict__ b1, const float* __restrict__ b2,
    const float* __restrict__ b3, const f16* __restrict__ ws,
    float* __restrict__ out) {
  extern __shared__ char smem[];
  f16* wbuf = (f16*)smem;              // 32*512 f16
  f16* pooled = wbuf + 32 * 512;       // 4*512 f16

  const int tid = threadIdx.x;
  const int wave = tid >> 6, lane = tid & 63;
  const int g = lane >> 4, r = lane & 15;

  // XCD-aware swizzle: 2048 wgs, 8 XCDs -> each XCD owns 256 contiguous wgs
  const int wg = (blockIdx.x & 7) * 256 + (blockIdx.x >> 3);
  const int b = wg >> 9;
  const int n0 = (wg & 511) * 16;
  const float* fb = f + (size_t)b * NN * CC;
  const int p0 = wave * 2;

  // --- issue knn index loads first (longest dependency chain) ---
  int nidx[2];
#pragma unroll
  for (int pp = 0; pp < 2; ++pp)
    nidx[pp] = knn[(size_t)(b * NN + n0 + p0 + pp) * KK + r];

  // --- stage 32 L1 weight frags into LDS (reg-staged, coalesced, linear) ---
  f16x8 st[4];
#pragma unroll
  for (int i = 0; i < 4; ++i)
    st[i] = *(const f16x8*)(ws + (size_t)(i * 512 + tid) * 8);
#pragma unroll
  for (int i = 0; i < 4; ++i)
    *(f16x8*)(wbuf + (size_t)(i * 512 + tid) * 8) = st[i];

  // --- gather B-frags: kt 0,1 = neighbor row (scattered), kt 2,3 = own row ---
  f16x8 bf[2][4];
#pragma unroll
  for (int pp = 0; pp < 2; ++pp) {
    const float* frow = fb + (size_t)nidx[pp] * CC;
    const float* fown = fb + (size_t)(n0 + p0 + pp) * CC;
#pragma unroll
    for (int kt = 0; kt < 4; ++kt) {
      const float* src = (kt < 2) ? (frow + kt * 32) : (fown + (kt - 2) * 32);
      f32x4 a0 = *(const f32x4*)(src + 4 * g);
      f32x4 a1 = *(const f32x4*)(src + 4 * g + 16);
      bf[pp][kt] = cvt8(a0, a1);
    }
  }

  __syncthreads();   // (1) wbuf ready

  // --- L1: C[h][nbr] = [Bm;Aw]^T x [knn;f], K=128; h1 -> registers ---
  f16x8 h1f[2][4];
#pragma unroll
  for (int ht = 0; ht < 8; ++ht) {
    f32x4 acc[2] = {{0.f, 0.f, 0.f, 0.f}, {0.f, 0.f, 0.f, 0.f}};
#pragma unroll
    for (int kt = 0; kt < 4; ++kt) {
      f16x8 wfrag = *(const f16x8*)(wbuf + (size_t)(ht * 4 + kt) * 512 + lane * 8);
      acc[0] = MFMA16(wfrag, bf[0][kt], acc[0]);
      acc[1] = MFMA16(wfrag, bf[1][kt], acc[1]);
    }
    f32x4 b1v = *(const f32x4*)(b1 + ht * 16 + g * 4);
#pragma unroll
    for (int pp = 0; pp < 2; ++pp) {
      float x0 = acc[pp][0] + b1v[0]; x0 = x0 > 0.f ? x0 : 0.f;
      float x1 = acc[pp][1] + b1v[1]; x1 = x1 > 0.f ? x1 : 0.f;
      float x2 = acc[pp][2] + b1v[2]; x2 = x2 > 0.f ? x2 : 0.f;
      float x3 = acc[pp][3] + b1v[3]; x3 = x3 > 0.f ? x3 : 0.f;
      h16x2 lo = __builtin_amdgcn_cvt_pkrtz(x0, x1);
      h16x2 hi = __builtin_amdgcn_cvt_pkrtz(x2, x3);
      h1f[pp][ht >> 1][(ht & 1) * 4 + 0] = (f16)lo[0];
      h1f[pp][ht >> 1][(ht & 1) * 4 + 1] = (f16)lo[1];
      h1f[pp][ht >> 1][(ht & 1) * 4 + 2] = (f16)hi[0];
      h1f[pp][ht >> 1][(ht & 1) * 4 + 3] = (f16)hi[1];
    }
  }

  // --- L2: C[nbr][h2] = h1 x W2 (W2 frags from GLOBAL ws, L1/L2-resident) ---
#pragma unroll
  for (int h2t = 0; h2t < 8; ++h2t) {
    f32x4 c0 = {0.f, 0.f, 0.f, 0.f}, c1 = {0.f, 0.f, 0.f, 0.f};
#pragma unroll
    for (int kt = 0; kt < 4; ++kt) {
      f16x8 w2f = *(const f16x8*)(ws + (size_t)(32 + h2t * 4 + kt) * 512 + lane * 8);
      c0 = MFMA16(h1f[0][kt], w2f, c0);
      c1 = MFMA16(h1f[1][kt], w2f, c1);
    }
    float b2v = b2[h2t * 16 + r];
#pragma unroll
    for (int pp = 0; pp < 2; ++pp) {
      f32x4 cc = pp ? c1 : c0;
      float m = fmaxf(fmaxf(cc[0], cc[1]), fmaxf(cc[2], cc[3]));
      m = fmaxf(m, __shfl_xor(m, 16, 64));
      m = fmaxf(m, __shfl_xor(m, 32, 64));
      float x = m + b2v;
      f16 pv = (f16)(x > 0.f ? x : 0.f);
      if (g == 0) {
        // dest: frag kt3=h2t>>1, lane slot (r>>2)*16 + p, elem (h2t&1)*4 + (r&3)
        pooled[(h2t >> 1) * 512 + ((r >> 2) * 16 + p0 + pp) * 8 +
               (h2t & 1) * 4 + (r & 3)] = pv;
      }
    }
  }

  __syncthreads();   // (2) pooled ready (cross-wave)

  // --- L3: C[od][pt] = W3^T x pooled; wave owns od-tile = wave ---
  {
    f32x4 a3 = {0.f, 0.f, 0.f, 0.f};
#pragma unroll
    for (int kt = 0; kt < 4; ++kt) {
      f16x8 w3f = *(const f16x8*)(ws + (size_t)(64 + wave * 4 + kt) * 512 + lane * 8);
      f16x8 pf = *(const f16x8*)(pooled + kt * 512 + lane * 8);
      a3 = MFMA16(w3f, pf, a3);
    }
    f32x4 b3v = *(const f32x4*)(b3 + wave * 16 + g * 4);
    f32x4 o;
#pragma unroll
    for (int i = 0; i < 4; ++i) o[i] = a3[i] + b3v[i];
    *(f32x4*)(out + ((size_t)b * NN + n0 + r) * HH + wave * 16 + g * 4) = o;
  }
}

extern "C" void kernel_launch(void* const* d_in, const int* in_sizes, int n_in,
                              void* d_out, int out_size, void* d_ws, size_t ws_size,
                              hipStream_t stream) {
  const float* f = (const float*)d_in[0];
  const int* knn = (const int*)d_in[1];
  const float* W1 = (const float*)d_in[2];
  const float* b1 = (const float*)d_in[3];
  const float* W2 = (const float*)d_in[4];
  const float* b2 = (const float*)d_in[5];
  const float* W3 = (const float*)d_in[6];
  const float* b3 = (const float*)d_in[7];
  float* outp = (float*)d_out;
  f16* wsp = (f16*)d_ws;   // 96 frags * 1KB = 96KB scratch

  (void)hipFuncSetAttribute((const void*)knn_main,
                            hipFuncAttributeMaxDynamicSharedMemorySize, 36864);

  prep_pack<<<96, 64, 0, stream>>>(W1, W2, W3, wsp);
  knn_main<<<(BB * NN) / 16, 512, 36864, stream>>>(f, knn, b1, b2, b3, wsp, outp);
}

// Round 9
// 57.966 us; speedup vs baseline: 4.0574x; 1.1452x over previous
//
#include <hip/hip_runtime.h>

// KnnConvUnit: B=4, N=8192, K=16, C=64, HID=OUT=128.
// out[b,n,:] = (max_k relu(relu(x@W1+b1)@W2+b2)) @ W3 + b3,
//   x = [f, knn, knn-f]  ->  h1 = relu([knn | f] @ [[Bm],[Aw]] + b1)
//   Bm = W1[64:128]+W1[128:192], Aw = W1[0:64]-W1[128:192]  (K=128 folded GEMM)
// v_mfma_f32_16x16x32_f16 everywhere, shared k-permutation
//   kappa(g,j) = 16*(j>>2) + 4*g + (j&3)
// Round-9 = round-8 shape (36.9KB LDS, 44 VGPR) + W2 RE-STAGED into wbuf:
//   stage Bm/Aw -> L1 -> barrier -> overwrite wbuf with W2 -> barrier -> L2.
//   All hot frag reads stay in LDS (round-2 property) while LDS/VGPR stay
//   small enough for 4 blocks/CU (round-8 property). sched_barrier(0) keeps
//   the st2 loads from hoisting into L1 (VGPR<=64 protection; rounds 4/7:
//   VGPR creep -> spill -> 3-10x regression).

#define BB 4
#define NN 8192
#define KK 16
#define CC 64
#define HH 128

typedef _Float16 f16;
typedef __fp16 h16x2 __attribute__((ext_vector_type(2)));   // cvt_pkrtz return type
typedef _Float16 f16x8 __attribute__((ext_vector_type(8)));
typedef float f32x4 __attribute__((ext_vector_type(4)));

#define MFMA16(a, b, c) __builtin_amdgcn_mfma_f32_16x16x32_f16(a, b, c, 0, 0, 0)

static __device__ __forceinline__ f16x8 cvt8(f32x4 a0, f32x4 a1) {
  h16x2 c0 = __builtin_amdgcn_cvt_pkrtz(a0[0], a0[1]);
  h16x2 c1 = __builtin_amdgcn_cvt_pkrtz(a0[2], a0[3]);
  h16x2 c2 = __builtin_amdgcn_cvt_pkrtz(a1[0], a1[1]);
  h16x2 c3 = __builtin_amdgcn_cvt_pkrtz(a1[2], a1[3]);
  f16x8 v;
  v[0] = (f16)c0[0]; v[1] = (f16)c0[1]; v[2] = (f16)c1[0]; v[3] = (f16)c1[1];
  v[4] = (f16)c2[0]; v[5] = (f16)c2[1]; v[6] = (f16)c3[0]; v[7] = (f16)c3[1];
  return v;
}

// ---------------- prep: pack weights, fragment-linear f16, kappa k-order ----
// fid 0..31 : L1 A-frags (ht=fid>>2, kt=fid&3): kt<2 -> Bm, kt>=2 -> Aw
// fid 32..63: L2 B-frags (h2t, kt): W2[k][h2t*16+r]
// fid 64..95: L3 A-frags (ot, kt):  W3[k][ot*16+r]
__global__ void prep_pack(const float* __restrict__ W1, const float* __restrict__ W2,
                          const float* __restrict__ W3, f16* __restrict__ ws) {
  int fid = blockIdx.x;
  int l = threadIdx.x;
  int g = l >> 4, r = l & 15;
  f16x8 v;
#pragma unroll
  for (int j = 0; j < 8; ++j) {
    int kl = 16 * (j >> 2) + 4 * g + (j & 3);   // kappa(g,j)
    float x;
    if (fid < 32) {
      int ht = fid >> 2, kt = fid & 3, h = ht * 16 + r;
      if (kt < 2) {
        int k = kt * 32 + kl;
        x = W1[(64 + k) * HH + h] + W1[(128 + k) * HH + h];   // Bm
      } else {
        int k = (kt - 2) * 32 + kl;
        x = W1[k * HH + h] - W1[(128 + k) * HH + h];          // Aw
      }
    } else if (fid < 64) {
      int t = fid - 32, h2t = t >> 2, kt = t & 3;
      x = W2[(kt * 32 + kl) * HH + h2t * 16 + r];
    } else {
      int t = fid - 64, ot = t >> 2, kt = t & 3;
      x = W3[(kt * 32 + kl) * HH + ot * 16 + r];
    }
    v[j] = (f16)x;
  }
  *(f16x8*)(ws + (size_t)fid * 512 + l * 8) = v;
}

// ---------------- main: 16 points/block, 8 waves, 2 pts/wave ----------------
// LDS: wbuf 32 frags (32KB, Bm/Aw then re-staged W2) + pooled 4 frags (4KB)
__global__ __launch_bounds__(512, 4) void knn_main(
    const float* __restrict__ f, const int* __restrict__ knn,
    const float* __restrict__ b1, const float* __restrict__ b2,
    const float* __restrict__ b3, const f16* __restrict__ ws,
    float* __restrict__ out) {
  extern __shared__ char smem[];
  f16* wbuf = (f16*)smem;              // 32*512 f16
  f16* pooled = wbuf + 32 * 512;       // 4*512 f16

  const int tid = threadIdx.x;
  const int wave = tid >> 6, lane = tid & 63;
  const int g = lane >> 4, r = lane & 15;

  // XCD-aware swizzle: 2048 wgs, 8 XCDs -> each XCD owns 256 contiguous wgs
  const int wg = (blockIdx.x & 7) * 256 + (blockIdx.x >> 3);
  const int b = wg >> 9;
  const int n0 = (wg & 511) * 16;
  const float* fb = f + (size_t)b * NN * CC;
  const int p0 = wave * 2;

  // --- issue knn index loads first (longest dependency chain) ---
  int nidx[2];
#pragma unroll
  for (int pp = 0; pp < 2; ++pp)
    nidx[pp] = knn[(size_t)(b * NN + n0 + p0 + pp) * KK + r];

  // --- stage 32 L1 weight frags (Bm/Aw) into LDS ---
  f16x8 st[4];
#pragma unroll
  for (int i = 0; i < 4; ++i)
    st[i] = *(const f16x8*)(ws + (size_t)(i * 512 + tid) * 8);
#pragma unroll
  for (int i = 0; i < 4; ++i)
    *(f16x8*)(wbuf + (size_t)(i * 512 + tid) * 8) = st[i];

  // --- gather B-frags: kt 0,1 = neighbor row (scattered), kt 2,3 = own row ---
  f16x8 bf[2][4];
#pragma unroll
  for (int pp = 0; pp < 2; ++pp) {
    const float* frow = fb + (size_t)nidx[pp] * CC;
    const float* fown = fb + (size_t)(n0 + p0 + pp) * CC;
#pragma unroll
    for (int kt = 0; kt < 4; ++kt) {
      const float* src = (kt < 2) ? (frow + kt * 32) : (fown + (kt - 2) * 32);
      f32x4 a0 = *(const f32x4*)(src + 4 * g);
      f32x4 a1 = *(const f32x4*)(src + 4 * g + 16);
      bf[pp][kt] = cvt8(a0, a1);
    }
  }

  __syncthreads();   // (1) wbuf = Bm/Aw ready

  // --- L1: C[h][nbr] = [Bm;Aw]^T x [knn;f], K=128; h1 -> registers ---
  f16x8 h1f[2][4];
#pragma unroll
  for (int ht = 0; ht < 8; ++ht) {
    f32x4 acc[2] = {{0.f, 0.f, 0.f, 0.f}, {0.f, 0.f, 0.f, 0.f}};
#pragma unroll
    for (int kt = 0; kt < 4; ++kt) {
      f16x8 wfrag = *(const f16x8*)(wbuf + (size_t)(ht * 4 + kt) * 512 + lane * 8);
      acc[0] = MFMA16(wfrag, bf[0][kt], acc[0]);
      acc[1] = MFMA16(wfrag, bf[1][kt], acc[1]);
    }
    f32x4 b1v = *(const f32x4*)(b1 + ht * 16 + g * 4);
#pragma unroll
    for (int pp = 0; pp < 2; ++pp) {
      float x0 = acc[pp][0] + b1v[0]; x0 = x0 > 0.f ? x0 : 0.f;
      float x1 = acc[pp][1] + b1v[1]; x1 = x1 > 0.f ? x1 : 0.f;
      float x2 = acc[pp][2] + b1v[2]; x2 = x2 > 0.f ? x2 : 0.f;
      float x3 = acc[pp][3] + b1v[3]; x3 = x3 > 0.f ? x3 : 0.f;
      h16x2 lo = __builtin_amdgcn_cvt_pkrtz(x0, x1);
      h16x2 hi = __builtin_amdgcn_cvt_pkrtz(x2, x3);
      h1f[pp][ht >> 1][(ht & 1) * 4 + 0] = (f16)lo[0];
      h1f[pp][ht >> 1][(ht & 1) * 4 + 1] = (f16)lo[1];
      h1f[pp][ht >> 1][(ht & 1) * 4 + 2] = (f16)hi[0];
      h1f[pp][ht >> 1][(ht & 1) * 4 + 3] = (f16)hi[1];
    }
  }

  __syncthreads();   // (2) all waves done reading Bm/Aw from wbuf
  __builtin_amdgcn_sched_barrier(0);   // don't hoist st2 loads into L1 (VGPR cap)

  // --- re-stage W2 frags (fid 32..63) into the SAME wbuf ---
  {
    f16x8 s2[4];
#pragma unroll
    for (int i = 0; i < 4; ++i)
      s2[i] = *(const f16x8*)(ws + (size_t)32 * 512 * 8 / 8 + (size_t)(i * 512 + tid) * 8 + 32 * 512 * 0);
#pragma unroll
    for (int i = 0; i < 4; ++i)
      *(f16x8*)(wbuf + (size_t)(i * 512 + tid) * 8) = s2[i];
  }

  __syncthreads();   // (3) wbuf = W2 ready

  // --- L2: C[nbr][h2] = h1 x W2 (frags from LDS); pool = 3 v_max + 2 shfl ---
#pragma unroll
  for (int h2t = 0; h2t < 8; ++h2t) {
    f32x4 c0 = {0.f, 0.f, 0.f, 0.f}, c1 = {0.f, 0.f, 0.f, 0.f};
#pragma unroll
    for (int kt = 0; kt < 4; ++kt) {
      f16x8 w2f = *(const f16x8*)(wbuf + (size_t)(h2t * 4 + kt) * 512 + lane * 8);
      c0 = MFMA16(h1f[0][kt], w2f, c0);
      c1 = MFMA16(h1f[1][kt], w2f, c1);
    }
    float b2v = b2[h2t * 16 + r];
#pragma unroll
    for (int pp = 0; pp < 2; ++pp) {
      f32x4 cc = pp ? c1 : c0;
      float m = fmaxf(fmaxf(cc[0], cc[1]), fmaxf(cc[2], cc[3]));
      m = fmaxf(m, __shfl_xor(m, 16, 64));
      m = fmaxf(m, __shfl_xor(m, 32, 64));
      float x = m + b2v;
      f16 pv = (f16)(x > 0.f ? x : 0.f);
      if (g == 0) {
        // dest: frag kt3=h2t>>1, lane slot (r>>2)*16 + p, elem (h2t&1)*4 + (r&3)
        pooled[(h2t >> 1) * 512 + ((r >> 2) * 16 + p0 + pp) * 8 +
               (h2t & 1) * 4 + (r & 3)] = pv;
      }
    }
  }

  __syncthreads();   // (4) pooled ready (cross-wave)

  // --- L3: C[od][pt] = W3^T x pooled; wave owns od-tile = wave ---
  {
    f32x4 a3 = {0.f, 0.f, 0.f, 0.f};
#pragma unroll
    for (int kt = 0; kt < 4; ++kt) {
      f16x8 w3f = *(const f16x8*)(ws + (size_t)(64 + wave * 4 + kt) * 512 + lane * 8);
      f16x8 pf = *(const f16x8*)(pooled + kt * 512 + lane * 8);
      a3 = MFMA16(w3f, pf, a3);
    }
    f32x4 b3v = *(const f32x4*)(b3 + wave * 16 + g * 4);
    f32x4 o;
#pragma unroll
    for (int i = 0; i < 4; ++i) o[i] = a3[i] + b3v[i];
    *(f32x4*)(out + ((size_t)b * NN + n0 + r) * HH + wave * 16 + g * 4) = o;
  }
}

extern "C" void kernel_launch(void* const* d_in, const int* in_sizes, int n_in,
                              void* d_out, int out_size, void* d_ws, size_t ws_size,
                              hipStream_t stream) {
  const float* f = (const float*)d_in[0];
  const int* knn = (const int*)d_in[1];
  const float* W1 = (const float*)d_in[2];
  const float* b1 = (const float*)d_in[3];
  const float* W2 = (const float*)d_in[4];
  const float* b2 = (const float*)d_in[5];
  const float* W3 = (const float*)d_in[6];
  const float* b3 = (const float*)d_in[7];
  float* outp = (float*)d_out;
  f16* wsp = (f16*)d_ws;   // 96 frags * 1KB = 96KB scratch

  (void)hipFuncSetAttribute((const void*)knn_main,
                            hipFuncAttributeMaxDynamicSharedMemorySize, 36864);

  prep_pack<<<96, 64, 0, stream>>>(W1, W2, W3, wsp);
  knn_main<<<(BB * NN) / 16, 512, 36864, stream>>>(f, knn, b1, b2, b3, wsp, outp);
}

// Round 10
// 53.322 us; speedup vs baseline: 4.4108x; 1.0871x over previous
//
#include <hip/hip_runtime.h>

// KnnConvUnit: B=4, N=8192, K=16, C=64, HID=OUT=128.
// out[b,n,:] = (max_k relu(relu(x@W1+b1)@W2+b2)) @ W3 + b3,
//   x = [f, knn, knn-f]  ->  h1 = relu([knn | f] @ [[Bm],[Aw]] + b1)
//   Bm = W1[64:128]+W1[128:192], Aw = W1[0:64]-W1[128:192]  (K=128 folded GEMM)
// v_mfma_f32_16x16x32_f16 everywhere, shared k-permutation
//   kappa(g,j) = 16*(j>>2) + 4*g + (j&3)
// Round-10 = round-2 skeleton (55.3us champion) + LDS-only barriers:
//   __syncthreads drains vmcnt(0) -> exposes full scattered-gather latency at
//   barrier (1). Cross-wave deps here are LDS-only, so use
//   s_waitcnt lgkmcnt(0) + raw s_barrier + sched_barrier(0) (rule #18), and
//   defer the NEIGHBOR cvt to after the barrier so its vmcnt wait lands
//   post-barrier, hidden under L1's ds_reads. W3 frags prefetched before
//   barrier (2) so they stay in flight across it.
//   Occupancy lesson (r8/r9): TLP knobs don't move perf; path length does.

#define BB 4
#define NN 8192
#define KK 16
#define CC 64
#define HH 128

typedef _Float16 f16;
typedef __fp16 h16x2 __attribute__((ext_vector_type(2)));   // cvt_pkrtz return type
typedef _Float16 f16x8 __attribute__((ext_vector_type(8)));
typedef float f32x4 __attribute__((ext_vector_type(4)));

#define MFMA16(a, b, c) __builtin_amdgcn_mfma_f32_16x16x32_f16(a, b, c, 0, 0, 0)

static __device__ __forceinline__ f16x8 cvt8(f32x4 a0, f32x4 a1) {
  h16x2 c0 = __builtin_amdgcn_cvt_pkrtz(a0[0], a0[1]);
  h16x2 c1 = __builtin_amdgcn_cvt_pkrtz(a0[2], a0[3]);
  h16x2 c2 = __builtin_amdgcn_cvt_pkrtz(a1[0], a1[1]);
  h16x2 c3 = __builtin_amdgcn_cvt_pkrtz(a1[2], a1[3]);
  f16x8 v;
  v[0] = (f16)c0[0]; v[1] = (f16)c0[1]; v[2] = (f16)c1[0]; v[3] = (f16)c1[1];
  v[4] = (f16)c2[0]; v[5] = (f16)c2[1]; v[6] = (f16)c3[0]; v[7] = (f16)c3[1];
  return v;
}

// LDS-only barrier: waits this wave's LDS ops, syncs waves, and pins the
// schedule so post-barrier LDS reads / cvts aren't hoisted above (rule #18).
// Crucially does NOT drain vmcnt -> global loads stay in flight across it.
static __device__ __forceinline__ void lds_barrier() {
  asm volatile("s_waitcnt lgkmcnt(0)" ::: "memory");
  __builtin_amdgcn_s_barrier();
  __builtin_amdgcn_sched_barrier(0);
}

// ---------------- prep: pack weights, fragment-linear f16, kappa k-order ----
// fid 0..31 : L1 A-frags (ht=fid>>2, kt=fid&3): kt<2 -> Bm, kt>=2 -> Aw
// fid 32..63: L2 B-frags (h2t, kt): W2[k][h2t*16+r]
// fid 64..95: L3 A-frags (ot, kt):  W3[k][ot*16+r]
__global__ void prep_pack(const float* __restrict__ W1, const float* __restrict__ W2,
                          const float* __restrict__ W3, f16* __restrict__ ws) {
  int fid = blockIdx.x;
  int l = threadIdx.x;
  int g = l >> 4, r = l & 15;
  f16x8 v;
#pragma unroll
  for (int j = 0; j < 8; ++j) {
    int kl = 16 * (j >> 2) + 4 * g + (j & 3);   // kappa(g,j)
    float x;
    if (fid < 32) {
      int ht = fid >> 2, kt = fid & 3, h = ht * 16 + r;
      if (kt < 2) {
        int k = kt * 32 + kl;
        x = W1[(64 + k) * HH + h] + W1[(128 + k) * HH + h];   // Bm
      } else {
        int k = (kt - 2) * 32 + kl;
        x = W1[k * HH + h] - W1[(128 + k) * HH + h];          // Aw
      }
    } else if (fid < 64) {
      int t = fid - 32, h2t = t >> 2, kt = t & 3;
      x = W2[(kt * 32 + kl) * HH + h2t * 16 + r];
    } else {
      int t = fid - 64, ot = t >> 2, kt = t & 3;
      x = W3[(kt * 32 + kl) * HH + ot * 16 + r];
    }
    v[j] = (f16)x;
  }
  *(f16x8*)(ws + (size_t)fid * 512 + l * 8) = v;
}

// ---------------- main: 16 points/block, 8 waves, 2 pts/wave ----------------
// LDS: wbuf 64 frags (Bm/Aw + W2, 64KB) + pooled 4 frags (4KB) = 69632 B
__global__ __launch_bounds__(512, 4) void knn_main(
    const float* __restrict__ f, const int* __restrict__ knn,
    const float* __restrict__ b1, const float* __restrict__ b2,
    const float* __restrict__ b3, const f16* __restrict__ ws,
    float* __restrict__ out) {
  extern __shared__ char smem[];
  f16* wbuf = (f16*)smem;              // 64*512 f16
  f16* pooled = wbuf + 64 * 512;       // 4*512 f16

  const int tid = threadIdx.x;
  const int wave = tid >> 6, lane = tid & 63;
  const int g = lane >> 4, r = lane & 15;

  // XCD-aware swizzle: 2048 wgs, 8 XCDs -> each XCD owns 256 contiguous wgs
  const int wg = (blockIdx.x & 7) * 256 + (blockIdx.x >> 3);
  const int b = wg >> 9;
  const int n0 = (wg & 511) * 16;
  const float* fb = f + (size_t)b * NN * CC;
  const int p0 = wave * 2;

  // --- issue knn index loads first (longest dependency chain) ---
  int nidx[2];
#pragma unroll
  for (int pp = 0; pp < 2; ++pp)
    nidx[pp] = knn[(size_t)(b * NN + n0 + p0 + pp) * KK + r];

  // --- stage 64 weight frags into LDS (reg-staged, coalesced, linear) ---
  f16x8 st[8];
#pragma unroll
  for (int i = 0; i < 8; ++i)
    st[i] = *(const f16x8*)(ws + (size_t)(i * 512 + tid) * 8);
#pragma unroll
  for (int i = 0; i < 8; ++i)
    *(f16x8*)(wbuf + (size_t)(i * 512 + tid) * 8) = st[i];

  // --- own rows (kt 2,3): load + cvt now (short chain, caps reg pressure) ---
  f16x8 bf[2][4];
#pragma unroll
  for (int pp = 0; pp < 2; ++pp) {
    const float* fown = fb + (size_t)(n0 + p0 + pp) * CC;
#pragma unroll
    for (int kt = 2; kt < 4; ++kt) {
      f32x4 a0 = *(const f32x4*)(fown + (kt - 2) * 32 + 4 * g);
      f32x4 a1 = *(const f32x4*)(fown + (kt - 2) * 32 + 4 * g + 16);
      bf[pp][kt] = cvt8(a0, a1);
    }
  }

  // --- neighbor rows (kt 0,1): ISSUE loads only; cvt deferred past barrier
  //     so the vmcnt wait lands after it (hidden under L1's ds_reads) ---
  f32x4 rawN[2][2][2];
#pragma unroll
  for (int pp = 0; pp < 2; ++pp) {
    const float* frow = fb + (size_t)nidx[pp] * CC;
#pragma unroll
    for (int kt = 0; kt < 2; ++kt) {
      rawN[pp][kt][0] = *(const f32x4*)(frow + kt * 32 + 4 * g);
      rawN[pp][kt][1] = *(const f32x4*)(frow + kt * 32 + 4 * g + 16);
    }
  }

  lds_barrier();   // (1) wbuf ready -- LDS-only wait; gathers still in flight

  // --- now convert the gathered neighbor rows ---
#pragma unroll
  for (int pp = 0; pp < 2; ++pp)
#pragma unroll
    for (int kt = 0; kt < 2; ++kt)
      bf[pp][kt] = cvt8(rawN[pp][kt][0], rawN[pp][kt][1]);

  // --- L1: C[h][nbr] = [Bm;Aw]^T x [knn;f], K=128; h1 -> registers ---
  f16x8 h1f[2][4];
#pragma unroll
  for (int ht = 0; ht < 8; ++ht) {
    f32x4 acc[2] = {{0.f, 0.f, 0.f, 0.f}, {0.f, 0.f, 0.f, 0.f}};
#pragma unroll
    for (int kt = 0; kt < 4; ++kt) {
      f16x8 wfrag = *(const f16x8*)(wbuf + (size_t)(ht * 4 + kt) * 512 + lane * 8);
      acc[0] = MFMA16(wfrag, bf[0][kt], acc[0]);
      acc[1] = MFMA16(wfrag, bf[1][kt], acc[1]);
    }
    f32x4 b1v = *(const f32x4*)(b1 + ht * 16 + g * 4);
#pragma unroll
    for (int pp = 0; pp < 2; ++pp) {
      float x0 = acc[pp][0] + b1v[0]; x0 = x0 > 0.f ? x0 : 0.f;
      float x1 = acc[pp][1] + b1v[1]; x1 = x1 > 0.f ? x1 : 0.f;
      float x2 = acc[pp][2] + b1v[2]; x2 = x2 > 0.f ? x2 : 0.f;
      float x3 = acc[pp][3] + b1v[3]; x3 = x3 > 0.f ? x3 : 0.f;
      h16x2 lo = __builtin_amdgcn_cvt_pkrtz(x0, x1);
      h16x2 hi = __builtin_amdgcn_cvt_pkrtz(x2, x3);
      h1f[pp][ht >> 1][(ht & 1) * 4 + 0] = (f16)lo[0];
      h1f[pp][ht >> 1][(ht & 1) * 4 + 1] = (f16)lo[1];
      h1f[pp][ht >> 1][(ht & 1) * 4 + 2] = (f16)hi[0];
      h1f[pp][ht >> 1][(ht & 1) * 4 + 3] = (f16)hi[1];
    }
  }

  // --- L2: C[nbr][h2] = h1 x W2 (frags 32..63 in wbuf); pool = max3 + 2 shfl ---
#pragma unroll
  for (int h2t = 0; h2t < 8; ++h2t) {
    f32x4 c0 = {0.f, 0.f, 0.f, 0.f}, c1 = {0.f, 0.f, 0.f, 0.f};
#pragma unroll
    for (int kt = 0; kt < 4; ++kt) {
      f16x8 w2f = *(const f16x8*)(wbuf + (size_t)(32 + h2t * 4 + kt) * 512 + lane * 8);
      c0 = MFMA16(h1f[0][kt], w2f, c0);
      c1 = MFMA16(h1f[1][kt], w2f, c1);
    }
    float b2v = b2[h2t * 16 + r];
#pragma unroll
    for (int pp = 0; pp < 2; ++pp) {
      f32x4 cc = pp ? c1 : c0;
      float m = fmaxf(fmaxf(cc[0], cc[1]), fmaxf(cc[2], cc[3]));
      m = fmaxf(m, __shfl_xor(m, 16, 64));
      m = fmaxf(m, __shfl_xor(m, 32, 64));
      float x = m + b2v;
      f16 pv = (f16)(x > 0.f ? x : 0.f);
      if (g == 0) {
        // dest: frag kt3=h2t>>1, lane slot (r>>2)*16 + p, elem (h2t&1)*4 + (r&3)
        pooled[(h2t >> 1) * 512 + ((r >> 2) * 16 + p0 + pp) * 8 +
               (h2t & 1) * 4 + (r & 3)] = pv;
      }
    }
  }

  // --- prefetch W3 frags from global BEFORE barrier (2): they cross it in
  //     flight since the raw barrier doesn't drain vmcnt ---
  f16x8 w3f[4];
#pragma unroll
  for (int kt = 0; kt < 4; ++kt)
    w3f[kt] = *(const f16x8*)(ws + (size_t)(64 + wave * 4 + kt) * 512 + lane * 8);

  lds_barrier();   // (2) pooled ready (cross-wave, LDS-only)

  // --- L3: C[od][pt] = W3^T x pooled; wave owns od-tile = wave ---
  {
    f32x4 a3 = {0.f, 0.f, 0.f, 0.f};
#pragma unroll
    for (int kt = 0; kt < 4; ++kt) {
      f16x8 pf = *(const f16x8*)(pooled + kt * 512 + lane * 8);
      a3 = MFMA16(w3f[kt], pf, a3);
    }
    f32x4 b3v = *(const f32x4*)(b3 + wave * 16 + g * 4);
    f32x4 o;
#pragma unroll
    for (int i = 0; i < 4; ++i) o[i] = a3[i] + b3v[i];
    *(f32x4*)(out + ((size_t)b * NN + n0 + r) * HH + wave * 16 + g * 4) = o;
  }
}

extern "C" void kernel_launch(void* const* d_in, const int* in_sizes, int n_in,
                              void* d_out, int out_size, void* d_ws, size_t ws_size,
                              hipStream_t stream) {
  const float* f = (const float*)d_in[0];
  const int* knn = (const int*)d_in[1];
  const float* W1 = (const float*)d_in[2];
  const float* b1 = (const float*)d_in[3];
  const float* W2 = (const float*)d_in[4];
  const float* b2 = (const float*)d_in[5];
  const float* W3 = (const float*)d_in[6];
  const float* b3 = (const float*)d_in[7];
  float* outp = (float*)d_out;
  f16* wsp = (f16*)d_ws;   // 96 frags * 1KB = 96KB scratch

  (void)hipFuncSetAttribute((const void*)knn_main,
                            hipFuncAttributeMaxDynamicSharedMemorySize, 69632);

  prep_pack<<<96, 64, 0, stream>>>(W1, W2, W3, wsp);
  knn_main<<<(BB * NN) / 16, 512, 69632, stream>>>(f, knn, b1, b2, b3, wsp, outp);
}